// Round 10
// baseline (50.443 us; speedup 1.0000x reference)
//
#include <hip/hip_runtime.h>

#define DIM     400
#define B       32
#define NCAND   14505
#define NROUND  3627      // ceil(NCAND/4) candidate quads
#define NSTRIP  512       // strips per batch-group
#define THREADS 256

// wave = 4 batch-slots x 16 dim-lanes. Slot g owns batch 4w+g's q/o (registers)
// AND loads candidate (4rr+g)'s row. 4 phases: compute vs resident cbuf, then
// XOR-rotate cbuf across slots (shfl_xor 16/32/16, cumulative masks 0,1,3,2).
// One candidate load serves 4 batches x 4 cands = 16 outputs -> L1 traffic /4.
__global__ __launch_bounds__(THREADS, 2)
void score_kernel(const float* __restrict__ ent,
                  const float* __restrict__ relc,
                  const float* __restrict__ relo,
                  const float* __restrict__ onev,
                  const int*   __restrict__ pairs,
                  const int*   __restrict__ cidx,
                  float* __restrict__ out) {
    const int fid  = blockIdx.x;
    const int xcd  = fid & 7;            // strip residue -> XCD L2 pinning
    const int rest = fid >> 3;
    const int w    = rest & 7;           // batch group (batches 4w..4w+3)
    const int sc   = rest >> 3;          // strip chunk 0..15
    const int tid  = threadIdx.x;
    const int wid  = tid >> 6;
    const int lane = tid & 63;
    const int u    = lane & 15;          // dim-lane
    const int g    = lane >> 4;          // slot = batch offset AND loaded-cand offset
    const int strip = xcd + 8 * (4 * sc + wid);   // 0..511
    const int b    = 4 * w + g;          // this lane's batch (per-lane, diverges by slot)

    // ---- one-time: q,o into registers; base = one + 0.98*sum(o) ----
    const int hd = pairs[b * 2 + 0];
    const int rl = pairs[b * 2 + 1];
    const float4* hb = (const float4*)(ent  + (size_t)hd * DIM) + u;
    const float4* cb = (const float4*)(relc + (size_t)rl * DIM) + u;
    const float4* ob = (const float4*)(relo + (size_t)rl * DIM) + u;

    float4 q[7], o[7];
    float oa = 0.f;
#pragma unroll
    for (int k = 0; k < 6; ++k) {
        float4 h = hb[16 * k], c = cb[16 * k];
        q[k] = make_float4(h.x + c.x, h.y + c.y, h.z + c.z, h.w + c.w);
        o[k] = ob[16 * k];
        oa += o[k].x + o[k].y + o[k].z + o[k].w;
    }
    if (u < 4) {
        float4 h = hb[96], c = cb[96];
        q[6] = make_float4(h.x + c.x, h.y + c.y, h.z + c.z, h.w + c.w);
        o[6] = ob[96];
        oa += o[6].x + o[6].y + o[6].z + o[6].w;
    }
    oa += __shfl_xor(oa, 1);
    oa += __shfl_xor(oa, 2);
    oa += __shfl_xor(oa, 4);
    oa += __shfl_xor(oa, 8);             // slot-local: full 400-dim sum for batch b
    const float base = onev[0] + 0.98f * oa;

    const float4* entu = (const float4*)ent + u;

#define E(vc, vq, vo, AM, AD)                     \
        {                                         \
            float d_ = (vc) - (vq);               \
            AM += fmaxf(fabsf(d_), (vo));         \
            AD += fabsf(d_);                      \
        }
#define F4(k, AM, AD)                             \
        E(cbuf[k].x, q[k].x, o[k].x, AM, AD)      \
        E(cbuf[k].y, q[k].y, o[k].y, AM, AD)      \
        E(cbuf[k].z, q[k].z, o[k].z, AM, AD)      \
        E(cbuf[k].w, q[k].w, o[k].w, AM, AD)

    // compute vs resident cbuf (holds cand cq + (g^m)), reduce over 16 dim-lanes, store
#define PHASE(m)                                                   \
    {                                                              \
        float am0 = 0.f, ad0 = 0.f, am1 = 0.f, ad1 = 0.f;          \
        F4(0, am0, ad0) F4(1, am1, ad1)                            \
        F4(2, am0, ad0) F4(3, am1, ad1)                            \
        F4(4, am0, ad0) F4(5, am1, ad1)                            \
        if (u < 4) { F4(6, am0, ad0) }                             \
        float s_ = fmaf(-0.98f, am0 + am1, -0.02f * (ad0 + ad1));  \
        s_ += __shfl_xor(s_, 1);                                   \
        s_ += __shfl_xor(s_, 2);                                   \
        s_ += __shfl_xor(s_, 4);                                   \
        s_ += __shfl_xor(s_, 8);                                   \
        const int cand_ = cq + (g ^ (m));                          \
        if (u == 0 && cand_ < NCAND)                               \
            out[(size_t)b * NCAND + cand_] = base + s_;            \
    }

#define ROT(mask)                                                  \
    {                                                              \
        _Pragma("unroll")                                          \
        for (int k = 0; k < 7; ++k) {                              \
            cbuf[k].x = __shfl_xor(cbuf[k].x, mask);               \
            cbuf[k].y = __shfl_xor(cbuf[k].y, mask);               \
            cbuf[k].z = __shfl_xor(cbuf[k].z, mask);               \
            cbuf[k].w = __shfl_xor(cbuf[k].w, mask);               \
        }                                                          \
    }

    for (int rr = strip; rr < NROUND; rr += NSTRIP) {
        const int cq  = 4 * rr;
        const int cl  = cq + g;
        const int ci  = cidx[cl < NCAND ? cl : NCAND - 1];   // clamp: harmless dup
        const float4* p = entu + (size_t)ci * 100;

        float4 cbuf[7];
#pragma unroll
        for (int k = 0; k < 6; ++k) cbuf[k] = p[16 * k];
        if (u < 4) cbuf[6] = p[96];

        PHASE(0)
        ROT(16)          // cumulative mask 1
        PHASE(1)
        ROT(32)          // cumulative mask 3
        PHASE(3)
        ROT(16)          // cumulative mask 2
        PHASE(2)
    }
#undef ROT
#undef PHASE
#undef F4
#undef E
}

extern "C" void kernel_launch(void* const* d_in, const int* in_sizes, int n_in,
                              void* d_out, int out_size, void* d_ws, size_t ws_size,
                              hipStream_t stream) {
    const float* ent   = (const float*)d_in[0];
    const float* relc  = (const float*)d_in[1];
    const float* relo  = (const float*)d_in[2];
    const float* onev  = (const float*)d_in[3];
    const int*   pairs = (const int*)d_in[4];
    const int*   cidx  = (const int*)d_in[5];
    float*       out   = (float*)d_out;

    const int grid = 8 * 8 * 16;   // 1024 = xcd(8) * bgroup(8) * strip-chunk(16)
    score_kernel<<<grid, THREADS, 0, stream>>>(ent, relc, relo, onev, pairs, cidx, out);
}

// Round 11
// 46.502 us; speedup vs baseline: 1.0848x; 1.0848x over previous
//
#include <hip/hip_runtime.h>

#define DIM     400
#define B       32
#define NCAND   14505
#define NROUND  3627      // ceil(NCAND/4) candidate quads
#define NSTRIP  128       // distinct strips; block stride in rr
#define THREADS 256

// wave = 4 cand-slots x 16 dim-lanes; lane u owns f4-chunks u+16k (k=0..5)
// plus tail chunk 96+u for u<4 (400 = 6*64 + 16).
// NB=2: lane holds q/o for batches b0=8*beta+wid and b1=b0+4 (112 VGPR) and
// computes BOTH against each candidate chunk -> candidate L1 bytes per output /2.
// 4 waves/block share the candidate strip (L1 reuse x4). No LDS, no atomics.
__global__ __launch_bounds__(THREADS)
void score_kernel(const float* __restrict__ ent,
                  const float* __restrict__ relc,
                  const float* __restrict__ relo,
                  const float* __restrict__ onev,
                  const int*   __restrict__ pairs,
                  const int*   __restrict__ cidx,
                  float* __restrict__ out) {
    const int fid  = blockIdx.x;
    const int xcd  = fid & 7;             // strip residue -> XCD L2 pinning
    const int rest = fid >> 3;
    const int beta = rest & 3;            // batch group (8 batches)
    const int sc   = rest >> 2;           // 0..15
    const int strip = xcd + 8 * sc;       // 0..127

    const int tid  = threadIdx.x;
    const int wid  = tid >> 6;
    const int lane = tid & 63;
    const int u    = lane & 15;           // dim-lane
    const int g    = lane >> 4;           // candidate slot 0..3

    const int b0 = __builtin_amdgcn_readfirstlane(8 * beta + wid);
    const int b1 = b0 + 4;

    // ---- one-time: q/o for both batches into registers; per-batch base ----
    const int h0 = pairs[b0 * 2 + 0], r0 = pairs[b0 * 2 + 1];
    const int h1 = pairs[b1 * 2 + 0], r1 = pairs[b1 * 2 + 1];
    const float4* h0p = (const float4*)(ent  + (size_t)h0 * DIM) + u;
    const float4* c0p = (const float4*)(relc + (size_t)r0 * DIM) + u;
    const float4* o0p = (const float4*)(relo + (size_t)r0 * DIM) + u;
    const float4* h1p = (const float4*)(ent  + (size_t)h1 * DIM) + u;
    const float4* c1p = (const float4*)(relc + (size_t)r1 * DIM) + u;
    const float4* o1p = (const float4*)(relo + (size_t)r1 * DIM) + u;

    float4 q0[7], o0[7], q1[7], o1[7];
    float oa0 = 0.f, oa1 = 0.f;
#pragma unroll
    for (int k = 0; k < 6; ++k) {
        float4 h = h0p[16 * k], c = c0p[16 * k];
        q0[k] = make_float4(h.x + c.x, h.y + c.y, h.z + c.z, h.w + c.w);
        o0[k] = o0p[16 * k];
        oa0 += o0[k].x + o0[k].y + o0[k].z + o0[k].w;
        h = h1p[16 * k]; c = c1p[16 * k];
        q1[k] = make_float4(h.x + c.x, h.y + c.y, h.z + c.z, h.w + c.w);
        o1[k] = o1p[16 * k];
        oa1 += o1[k].x + o1[k].y + o1[k].z + o1[k].w;
    }
    if (u < 4) {
        float4 h = h0p[96], c = c0p[96];
        q0[6] = make_float4(h.x + c.x, h.y + c.y, h.z + c.z, h.w + c.w);
        o0[6] = o0p[96];
        oa0 += o0[6].x + o0[6].y + o0[6].z + o0[6].w;
        h = h1p[96]; c = c1p[96];
        q1[6] = make_float4(h.x + c.x, h.y + c.y, h.z + c.z, h.w + c.w);
        o1[6] = o1p[96];
        oa1 += o1[6].x + o1[6].y + o1[6].z + o1[6].w;
    }
    // sum over the 16 dim-lanes (all slots/duplicate groups identical)
    oa0 += __shfl_xor(oa0, 1); oa1 += __shfl_xor(oa1, 1);
    oa0 += __shfl_xor(oa0, 2); oa1 += __shfl_xor(oa1, 2);
    oa0 += __shfl_xor(oa0, 4); oa1 += __shfl_xor(oa1, 4);
    oa0 += __shfl_xor(oa0, 8); oa1 += __shfl_xor(oa1, 8);
    const float onec  = onev[0];
    const float base0 = onec + 0.98f * oa0;
    const float base1 = onec + 0.98f * oa1;

    const float4* entu = (const float4*)ent + u;

#define E(vc, vq, vo, AM, AD)                     \
        {                                         \
            float d_ = (vc) - (vq);               \
            AM += fmaxf(fabsf(d_), (vo));         \
            AD += fabsf(d_);                      \
        }
#define F4(k)                                                   \
        E(cbuf[k].x, q0[k].x, o0[k].x, am0, ad0)                \
        E(cbuf[k].x, q1[k].x, o1[k].x, am1, ad1)                \
        E(cbuf[k].y, q0[k].y, o0[k].y, am0, ad0)                \
        E(cbuf[k].y, q1[k].y, o1[k].y, am1, ad1)                \
        E(cbuf[k].z, q0[k].z, o0[k].z, am0, ad0)                \
        E(cbuf[k].z, q1[k].z, o1[k].z, am1, ad1)                \
        E(cbuf[k].w, q0[k].w, o0[k].w, am0, ad0)                \
        E(cbuf[k].w, q1[k].w, o1[k].w, am1, ad1)

    for (int rr = strip; rr < NROUND; rr += NSTRIP) {
        const int cq = 4 * rr;
        const int cl = cq + g;
        const int ci = cidx[cl < NCAND ? cl : NCAND - 1];   // clamp: harmless dup
        const float4* p = entu + (size_t)ci * 100;

        float4 cbuf[7];
#pragma unroll
        for (int k = 0; k < 6; ++k) cbuf[k] = p[16 * k];
        if (u < 4) cbuf[6] = p[96];

        float am0 = 0.f, ad0 = 0.f, am1 = 0.f, ad1 = 0.f;
        F4(0) F4(1) F4(2) F4(3) F4(4) F4(5)
        if (u < 4) { F4(6) }

        float s0 = fmaf(-0.98f, am0, -0.02f * ad0);
        float s1 = fmaf(-0.98f, am1, -0.02f * ad1);
        s0 += __shfl_xor(s0, 1); s1 += __shfl_xor(s1, 1);
        s0 += __shfl_xor(s0, 2); s1 += __shfl_xor(s1, 2);
        s0 += __shfl_xor(s0, 4); s1 += __shfl_xor(s1, 4);
        s0 += __shfl_xor(s0, 8); s1 += __shfl_xor(s1, 8);

        if (u == 0 && cl < NCAND) {
            out[(size_t)b0 * NCAND + cl] = base0 + s0;   // lanes 0/16/32/48: 16B segment
            out[(size_t)b1 * NCAND + cl] = base1 + s1;
        }
    }
#undef F4
#undef E
}

extern "C" void kernel_launch(void* const* d_in, const int* in_sizes, int n_in,
                              void* d_out, int out_size, void* d_ws, size_t ws_size,
                              hipStream_t stream) {
    const float* ent   = (const float*)d_in[0];
    const float* relc  = (const float*)d_in[1];
    const float* relo  = (const float*)d_in[2];
    const float* onev  = (const float*)d_in[3];
    const int*   pairs = (const int*)d_in[4];
    const int*   cidx  = (const int*)d_in[5];
    float*       out   = (float*)d_out;

    const int grid = 8 * 4 * 16;   // 512 = xcd(8) * bgroup(4) * strip-chunk(16)
    score_kernel<<<grid, THREADS, 0, stream>>>(ent, relc, relo, onev, pairs, cidx, out);
}

// Round 13
// 45.865 us; speedup vs baseline: 1.0998x; 1.0139x over previous
//
#include <hip/hip_runtime.h>

#define DIM     400
#define NENT    14541
#define B       32
#define NCAND   14505
#define NROUND  3627      // ceil(NCAND/4) candidate quads
#define TSTRIPS 256
#define THREADS 256

typedef __attribute__((ext_vector_type(2))) _Float16 half2_t;

static __device__ __forceinline__ half2_t bch(unsigned u) {
    return __builtin_bit_cast(half2_t, u);
}
static __device__ __forceinline__ half2_t habs2(half2_t x) {
    unsigned u = __builtin_bit_cast(unsigned, x) & 0x7fff7fffu;
    return __builtin_bit_cast(half2_t, u);
}
static __device__ __forceinline__ unsigned pkh(float x, float y) {
    half2_t h;
    h.x = (_Float16)x;
    h.y = (_Float16)y;
    return __builtin_bit_cast(unsigned, h);
}
static __device__ __forceinline__ float dot2acc(half2_t m, float s) {
#if __has_builtin(__builtin_amdgcn_fdot2)
    const half2_t ones = {(_Float16)1.f, (_Float16)1.f};
    return __builtin_amdgcn_fdot2(m, ones, s, false);
#else
    return s + (float)m.x + (float)m.y;
#endif
}

// ---- setup 1: ent (f32) -> ent16 (f16), 8 elems/thread ----
__global__ void cvt_kernel(const float* __restrict__ ent, uint4* __restrict__ dst) {
    const int TOT8 = NENT * DIM / 8;   // 727050
    int i = blockIdx.x * THREADS + threadIdx.x;
    if (i >= TOT8) return;
    const float4* s4 = (const float4*)ent;
    float4 a = s4[2 * i], b = s4[2 * i + 1];
    uint4 o;
    o.x = pkh(a.x, a.y);
    o.y = pkh(a.z, a.w);
    o.z = pkh(b.x, b.y);
    o.w = pkh(b.z, b.w);
    dst[i] = o;
}

// ---- setup 2: q16[b]=half(h+rc), o16[b]=half(0.98*o), base[b]=one+0.98*sum(o) ----
__global__ void prep_kernel(const float* __restrict__ ent,
                            const float* __restrict__ relc,
                            const float* __restrict__ relo,
                            const float* __restrict__ onev,
                            const int*   __restrict__ pairs,
                            _Float16* __restrict__ q16,
                            _Float16* __restrict__ o16,
                            float* __restrict__ baseg) {
    const int b   = blockIdx.x;
    const int tid = threadIdx.x;
    const int h = pairs[2 * b + 0];
    const int r = pairs[2 * b + 1];
    float so = 0.f;
    for (int i = tid; i < DIM; i += THREADS) {
        float qv = ent[(size_t)h * DIM + i] + relc[(size_t)r * DIM + i];
        float ov = relo[(size_t)r * DIM + i];
        q16[(size_t)b * DIM + i] = (_Float16)qv;
        o16[(size_t)b * DIM + i] = (_Float16)(0.98f * ov);
        so += ov;
    }
    __shared__ float sred[4];
    for (int off = 32; off; off >>= 1) so += __shfl_down(so, off);
    if ((tid & 63) == 0) sred[tid >> 6] = so;
    __syncthreads();
    if (tid == 0)
        baseg[b] = onev[0] + 0.98f * (sred[0] + sred[1] + sred[2] + sred[3]);
}

// ---- main (f16): wave = 4 cand-slots x 16 dim-lanes; lane u owns uint4-chunks
// u+16k (k=0..2) + tail 48+u (u<2); 50 uint4 = 400 halves per row.
// Per pair: pk_sub, and-abs, pk_fma, pk_max, dot2-f32-acc = 2.5 VALU/elem.
// contribution = max(|d|, 0.02|d| + 0.98o); out = base - sum.
__global__ __launch_bounds__(THREADS, 2)
void score_f16(const uint4* __restrict__ ent16,
               const uint4* __restrict__ q16,
               const uint4* __restrict__ o16,
               const float* __restrict__ baseg,
               const int*   __restrict__ cidx,
               float* __restrict__ out) {
    const int fid  = blockIdx.x;
    const int xcd  = fid & 7;            // strip residue -> XCD L2 pinning
    const int rest = fid >> 3;
    const int bq   = rest & 7;
    const int tc   = rest >> 3;          // 0..31
    const int t    = xcd + 8 * tc;       // strip 0..255

    const int tid  = threadIdx.x;
    const int lane = tid & 63;
    const int u    = lane & 15;
    const int g    = lane >> 4;
    const int b    = __builtin_amdgcn_readfirstlane(bq * 4 + (tid >> 6));

    const uint4* qb = q16 + (size_t)b * 50;
    const uint4* ob = o16 + (size_t)b * 50;
    uint4 qr0 = qb[u], qr1 = qb[u + 16], qr2 = qb[u + 32];
    uint4 or0 = ob[u], or1 = ob[u + 16], or2 = ob[u + 32];
    uint4 qr3 = qr0, or3 = or0;
    if (u < 2) { qr3 = qb[48 + u]; or3 = ob[48 + u]; }
    const float base = baseg[b];

    const half2_t K002 = {(_Float16)0.02f, (_Float16)0.02f};

#define PAIR(cu, qu, ou)                                        \
    {                                                           \
        half2_t cc_ = bch(cu), qq_ = bch(qu), oo_ = bch(ou);    \
        half2_t dd_ = cc_ - qq_;                                \
        half2_t aa_ = habs2(dd_);                               \
        half2_t ee_ = aa_ * K002 + oo_;                         \
        half2_t mm_ = __builtin_elementwise_max(aa_, ee_);      \
        s = dot2acc(mm_, s);                                    \
    }
#define PROC(C, Q, O) \
    PAIR(C.x, Q.x, O.x) PAIR(C.y, Q.y, O.y) PAIR(C.z, Q.z, O.z) PAIR(C.w, Q.w, O.w)

    for (int rr = t; rr < NROUND; rr += TSTRIPS) {
        const int cand = 4 * rr + g;
        const int ci   = cidx[cand < NCAND ? cand : NCAND - 1];  // clamp: harmless dup
        const uint4* p = ent16 + (size_t)ci * 50;

        uint4 cv0 = p[u], cv1 = p[u + 16], cv2 = p[u + 32];
        uint4 cv3;
        if (u < 2) cv3 = p[48 + u];

        float s = 0.f;
        PROC(cv0, qr0, or0)
        PROC(cv1, qr1, or1)
        PROC(cv2, qr2, or2)
        if (u < 2) { PROC(cv3, qr3, or3) }

        s += __shfl_xor(s, 1);
        s += __shfl_xor(s, 2);
        s += __shfl_xor(s, 4);
        s += __shfl_xor(s, 8);

        if (u == 0 && cand < NCAND)
            out[(size_t)b * NCAND + cand] = base - s;   // lanes 0/16/32/48: 16B segment
    }
#undef PROC
#undef PAIR
}

// ---- fallback (no ws): R9 f32 kernel verbatim ----
__global__ __launch_bounds__(THREADS, 2)
void score_f32(const float* __restrict__ ent,
               const float* __restrict__ relc,
               const float* __restrict__ relo,
               const float* __restrict__ onev,
               const int*   __restrict__ pairs,
               const int*   __restrict__ cidx,
               float* __restrict__ out) {
    const int fid  = blockIdx.x;
    const int xcd  = fid & 7;
    const int rest = fid >> 3;
    const int bq   = rest & 7;
    const int tc   = rest >> 3;
    const int t    = xcd + 8 * tc;

    const int tid  = threadIdx.x;
    const int lane = tid & 63;
    const int u    = lane & 15;
    const int g    = lane >> 4;
    const int b    = __builtin_amdgcn_readfirstlane(bq * 4 + (tid >> 6));

    const int hd = pairs[b * 2 + 0];
    const int rl = pairs[b * 2 + 1];
    const float4* hb = (const float4*)(ent  + (size_t)hd * DIM) + u;
    const float4* cb = (const float4*)(relc + (size_t)rl * DIM) + u;
    const float4* ob = (const float4*)(relo + (size_t)rl * DIM) + u;

    float4 q[7], o[7];
    float oa = 0.f;
#pragma unroll
    for (int k = 0; k < 6; ++k) {
        float4 h = hb[16 * k], c = cb[16 * k];
        q[k] = make_float4(h.x + c.x, h.y + c.y, h.z + c.z, h.w + c.w);
        o[k] = ob[16 * k];
        oa += o[k].x + o[k].y + o[k].z + o[k].w;
    }
    if (u < 4) {
        float4 h = hb[96], c = cb[96];
        q[6] = make_float4(h.x + c.x, h.y + c.y, h.z + c.z, h.w + c.w);
        o[6] = ob[96];
        oa += o[6].x + o[6].y + o[6].z + o[6].w;
    }
    oa += __shfl_xor(oa, 1);
    oa += __shfl_xor(oa, 2);
    oa += __shfl_xor(oa, 4);
    oa += __shfl_xor(oa, 8);
    const float base = onev[0] + 0.98f * oa;

    const float4* entu = (const float4*)ent + u;

#define E(vc, vq, vo, AM, AD)                     \
        {                                         \
            float d_ = (vc) - (vq);               \
            AM += fmaxf(fabsf(d_), (vo));         \
            AD += fabsf(d_);                      \
        }
#define F4(k, AM, AD)                             \
        E(cbuf[k].x, q[k].x, o[k].x, AM, AD)      \
        E(cbuf[k].y, q[k].y, o[k].y, AM, AD)      \
        E(cbuf[k].z, q[k].z, o[k].z, AM, AD)      \
        E(cbuf[k].w, q[k].w, o[k].w, AM, AD)

    for (int rr = t; rr < NROUND; rr += TSTRIPS) {
        const int cand = 4 * rr + g;
        const int ci   = cidx[cand < NCAND ? cand : NCAND - 1];
        const float4* p = entu + (size_t)ci * 100;

        float4 cbuf[7];
#pragma unroll
        for (int k = 0; k < 6; ++k) cbuf[k] = p[16 * k];
        if (u < 4) cbuf[6] = p[96];

        float am0 = 0.f, ad0 = 0.f, am1 = 0.f, ad1 = 0.f;
        F4(0, am0, ad0) F4(1, am1, ad1)
        F4(2, am0, ad0) F4(3, am1, ad1)
        F4(4, am0, ad0) F4(5, am1, ad1)
        if (u < 4) { F4(6, am0, ad0) }

        float s_ = fmaf(-0.98f, am0 + am1, -0.02f * (ad0 + ad1));
        s_ += __shfl_xor(s_, 1);
        s_ += __shfl_xor(s_, 2);
        s_ += __shfl_xor(s_, 4);
        s_ += __shfl_xor(s_, 8);

        if (u == 0 && cand < NCAND)
            out[(size_t)b * NCAND + cand] = base + s_;
    }
#undef F4
#undef E
}

extern "C" void kernel_launch(void* const* d_in, const int* in_sizes, int n_in,
                              void* d_out, int out_size, void* d_ws, size_t ws_size,
                              hipStream_t stream) {
    const float* ent   = (const float*)d_in[0];
    const float* relc  = (const float*)d_in[1];
    const float* relo  = (const float*)d_in[2];
    const float* onev  = (const float*)d_in[3];
    const int*   pairs = (const int*)d_in[4];
    const int*   cidx  = (const int*)d_in[5];
    float*       out   = (float*)d_out;

    const size_t entB = (size_t)NENT * DIM * 2;      // 11,632,800 (16B-aligned)
    const size_t qB   = (size_t)B * DIM * 2;         // 25,600
    const size_t need = entB + 2 * qB + B * sizeof(float);
    const int grid = 8 * 8 * 32;                     // 2048

    if (ws_size >= need) {
        unsigned char* w = (unsigned char*)d_ws;
        uint4*    ent16 = (uint4*)w;
        _Float16* q16   = (_Float16*)(w + entB);
        _Float16* o16   = (_Float16*)(w + entB + qB);
        float*    baseg = (float*)(w + entB + 2 * qB);

        const int TOT8 = NENT * DIM / 8;             // 727050
        cvt_kernel<<<(TOT8 + THREADS - 1) / THREADS, THREADS, 0, stream>>>(ent, ent16);
        prep_kernel<<<B, THREADS, 0, stream>>>(ent, relc, relo, onev, pairs, q16, o16, baseg);
        score_f16<<<grid, THREADS, 0, stream>>>(
            ent16, (const uint4*)q16, (const uint4*)o16, baseg, cidx, out);
    } else {
        score_f32<<<grid, THREADS, 0, stream>>>(ent, relc, relo, onev, pairs, cidx, out);
    }
}

// Round 14
// 41.824 us; speedup vs baseline: 1.2061x; 1.0966x over previous
//
#include <hip/hip_runtime.h>

#define DIM     400
#define NENT    14541
#define B       32
#define NCAND   14505
#define NROUND  3627      // ceil(NCAND/4) candidate quads
#define TSTRIPS 256
#define THREADS 256
#define CVTBLK  2841      // ceil(NENT*DIM/8 / 256)

typedef __attribute__((ext_vector_type(2))) _Float16 half2_t;

static __device__ __forceinline__ half2_t bch(unsigned u) {
    return __builtin_bit_cast(half2_t, u);
}
static __device__ __forceinline__ half2_t habs2(half2_t x) {
    unsigned u = __builtin_bit_cast(unsigned, x) & 0x7fff7fffu;
    return __builtin_bit_cast(half2_t, u);
}
static __device__ __forceinline__ unsigned pkh(float x, float y) {
    half2_t h;
    h.x = (_Float16)x;
    h.y = (_Float16)y;
    return __builtin_bit_cast(unsigned, h);
}
static __device__ __forceinline__ float dot2acc(half2_t m, float s) {
#if __has_builtin(__builtin_amdgcn_fdot2)
    const half2_t ones = {(_Float16)1.f, (_Float16)1.f};
    return __builtin_amdgcn_fdot2(m, ones, s, false);
#else
    return s + (float)m.x + (float)m.y;
#endif
}

// ---- merged setup: blocks [0,CVTBLK) convert ent->f16; blocks [CVTBLK,CVTBLK+32) prep q/o/base
__global__ void setup_kernel(const float* __restrict__ ent,
                             const float* __restrict__ relc,
                             const float* __restrict__ relo,
                             const float* __restrict__ onev,
                             const int*   __restrict__ pairs,
                             uint4* __restrict__ ent16,
                             _Float16* __restrict__ q16,
                             _Float16* __restrict__ o16,
                             float* __restrict__ baseg) {
    const int blk = blockIdx.x;
    const int tid = threadIdx.x;
    if (blk < CVTBLK) {
        const int TOT8 = NENT * DIM / 8;   // 727050
        int i = blk * THREADS + tid;
        if (i >= TOT8) return;
        const float4* s4 = (const float4*)ent;
        float4 a = s4[2 * i], c = s4[2 * i + 1];
        uint4 d;
        d.x = pkh(a.x, a.y);
        d.y = pkh(a.z, a.w);
        d.z = pkh(c.x, c.y);
        d.w = pkh(c.z, c.w);
        ent16[i] = d;
    } else {
        const int b = blk - CVTBLK;
        const int h = pairs[2 * b + 0];
        const int r = pairs[2 * b + 1];
        float so = 0.f;
        for (int i = tid; i < DIM; i += THREADS) {
            float qv = ent[(size_t)h * DIM + i] + relc[(size_t)r * DIM + i];
            float ov = relo[(size_t)r * DIM + i];
            q16[(size_t)b * DIM + i] = (_Float16)qv;
            o16[(size_t)b * DIM + i] = (_Float16)(0.98f * ov);
            so += ov;
        }
        __shared__ float sred[4];
        for (int off = 32; off; off >>= 1) so += __shfl_down(so, off);
        if ((tid & 63) == 0) sred[tid >> 6] = so;
        __syncthreads();
        if (tid == 0)
            baseg[b] = onev[0] + 0.98f * (sred[0] + sred[1] + sred[2] + sred[3]);
    }
}

// ---- main (f16, 2 quads/round): wave = 4 cand-slots x 16 dim-lanes; lane u owns
// uint4-chunks u+16k (k=0..2) + tail 48+u (u<2). Each iteration processes quads
// rr (strip t) and rr+TSTRIPS (strip t+256, same XCD residue): 8 loads, 2x ~80 VALU,
// 4 independent fdot2 chains, 2 reduces, 2 stores -> per-round overhead amortized 2x.
__global__ __launch_bounds__(THREADS, 2)
void score_f16(const uint4* __restrict__ ent16,
               const uint4* __restrict__ q16,
               const uint4* __restrict__ o16,
               const float* __restrict__ baseg,
               const int*   __restrict__ cidx,
               float* __restrict__ out) {
    const int fid  = blockIdx.x;
    const int xcd  = fid & 7;            // strip residue -> XCD L2 pinning
    const int rest = fid >> 3;
    const int bq   = rest & 7;
    const int tc   = rest >> 3;          // 0..31
    const int t    = xcd + 8 * tc;       // strip 0..255

    const int tid  = threadIdx.x;
    const int lane = tid & 63;
    const int u    = lane & 15;
    const int g    = lane >> 4;
    const int b    = __builtin_amdgcn_readfirstlane(bq * 4 + (tid >> 6));

    const uint4* qb = q16 + (size_t)b * 50;
    const uint4* ob = o16 + (size_t)b * 50;
    uint4 qr0 = qb[u], qr1 = qb[u + 16], qr2 = qb[u + 32];
    uint4 or0 = ob[u], or1 = ob[u + 16], or2 = ob[u + 32];
    uint4 qr3 = qr0, or3 = or0;
    if (u < 2) { qr3 = qb[48 + u]; or3 = ob[48 + u]; }
    const float base = baseg[b];

    const half2_t K002 = {(_Float16)0.02f, (_Float16)0.02f};

#define PAIR(cu, qu, ou, SS)                                    \
    {                                                           \
        half2_t cc_ = bch(cu), qq_ = bch(qu), oo_ = bch(ou);    \
        half2_t dd_ = cc_ - qq_;                                \
        half2_t aa_ = habs2(dd_);                               \
        half2_t ee_ = aa_ * K002 + oo_;                         \
        half2_t mm_ = __builtin_elementwise_max(aa_, ee_);      \
        SS = dot2acc(mm_, SS);                                  \
    }
#define PROC(C, Q, O, SA, SB)                                   \
    PAIR(C.x, Q.x, O.x, SA) PAIR(C.y, Q.y, O.y, SB)             \
    PAIR(C.z, Q.z, O.z, SA) PAIR(C.w, Q.w, O.w, SB)

    for (int rr = t; rr < NROUND; rr += 2 * TSTRIPS) {
        const int rrB   = rr + TSTRIPS;
        const int candA = 4 * rr + g;
        const int candB = 4 * rrB + g;
        const int ciA = cidx[candA < NCAND ? candA : NCAND - 1];
        const int ciB = cidx[candB < NCAND ? candB : NCAND - 1];
        const uint4* pA = ent16 + (size_t)ciA * 50;
        const uint4* pB = ent16 + (size_t)ciB * 50;

        uint4 a0 = pA[u], a1 = pA[u + 16], a2 = pA[u + 32];
        uint4 b0 = pB[u], b1 = pB[u + 16], b2 = pB[u + 32];
        uint4 a3, b3;
        if (u < 2) { a3 = pA[48 + u]; b3 = pB[48 + u]; }

        float sa0 = 0.f, sa1 = 0.f, sb0 = 0.f, sb1 = 0.f;   // 4 independent chains
        PROC(a0, qr0, or0, sa0, sa1)
        PROC(a1, qr1, or1, sa0, sa1)
        PROC(a2, qr2, or2, sa0, sa1)
        if (u < 2) { PROC(a3, qr3, or3, sa0, sa1) }
        PROC(b0, qr0, or0, sb0, sb1)
        PROC(b1, qr1, or1, sb0, sb1)
        PROC(b2, qr2, or2, sb0, sb1)
        if (u < 2) { PROC(b3, qr3, or3, sb0, sb1) }

        float sA = sa0 + sa1;
        float sB = sb0 + sb1;
        sA += __shfl_xor(sA, 1); sB += __shfl_xor(sB, 1);
        sA += __shfl_xor(sA, 2); sB += __shfl_xor(sB, 2);
        sA += __shfl_xor(sA, 4); sB += __shfl_xor(sB, 4);
        sA += __shfl_xor(sA, 8); sB += __shfl_xor(sB, 8);

        if (u == 0) {
            if (candA < NCAND) out[(size_t)b * NCAND + candA] = base - sA;
            if (candB < NCAND) out[(size_t)b * NCAND + candB] = base - sB;
        }
    }
#undef PROC
#undef PAIR
}

// ---- fallback (no ws): R9 f32 kernel verbatim ----
__global__ __launch_bounds__(THREADS, 2)
void score_f32(const float* __restrict__ ent,
               const float* __restrict__ relc,
               const float* __restrict__ relo,
               const float* __restrict__ onev,
               const int*   __restrict__ pairs,
               const int*   __restrict__ cidx,
               float* __restrict__ out) {
    const int fid  = blockIdx.x;
    const int xcd  = fid & 7;
    const int rest = fid >> 3;
    const int bq   = rest & 7;
    const int tc   = rest >> 3;
    const int t    = xcd + 8 * tc;

    const int tid  = threadIdx.x;
    const int lane = tid & 63;
    const int u    = lane & 15;
    const int g    = lane >> 4;
    const int b    = __builtin_amdgcn_readfirstlane(bq * 4 + (tid >> 6));

    const int hd = pairs[b * 2 + 0];
    const int rl = pairs[b * 2 + 1];
    const float4* hb = (const float4*)(ent  + (size_t)hd * DIM) + u;
    const float4* cb = (const float4*)(relc + (size_t)rl * DIM) + u;
    const float4* ob = (const float4*)(relo + (size_t)rl * DIM) + u;

    float4 q[7], o[7];
    float oa = 0.f;
#pragma unroll
    for (int k = 0; k < 6; ++k) {
        float4 h = hb[16 * k], c = cb[16 * k];
        q[k] = make_float4(h.x + c.x, h.y + c.y, h.z + c.z, h.w + c.w);
        o[k] = ob[16 * k];
        oa += o[k].x + o[k].y + o[k].z + o[k].w;
    }
    if (u < 4) {
        float4 h = hb[96], c = cb[96];
        q[6] = make_float4(h.x + c.x, h.y + c.y, h.z + c.z, h.w + c.w);
        o[6] = ob[96];
        oa += o[6].x + o[6].y + o[6].z + o[6].w;
    }
    oa += __shfl_xor(oa, 1);
    oa += __shfl_xor(oa, 2);
    oa += __shfl_xor(oa, 4);
    oa += __shfl_xor(oa, 8);
    const float base = onev[0] + 0.98f * oa;

    const float4* entu = (const float4*)ent + u;

#define E(vc, vq, vo, AM, AD)                     \
        {                                         \
            float d_ = (vc) - (vq);               \
            AM += fmaxf(fabsf(d_), (vo));         \
            AD += fabsf(d_);                      \
        }
#define F4(k, AM, AD)                             \
        E(cbuf[k].x, q[k].x, o[k].x, AM, AD)      \
        E(cbuf[k].y, q[k].y, o[k].y, AM, AD)      \
        E(cbuf[k].z, q[k].z, o[k].z, AM, AD)      \
        E(cbuf[k].w, q[k].w, o[k].w, AM, AD)

    for (int rr = t; rr < NROUND; rr += TSTRIPS) {
        const int cand = 4 * rr + g;
        const int ci   = cidx[cand < NCAND ? cand : NCAND - 1];
        const float4* p = entu + (size_t)ci * 100;

        float4 cbuf[7];
#pragma unroll
        for (int k = 0; k < 6; ++k) cbuf[k] = p[16 * k];
        if (u < 4) cbuf[6] = p[96];

        float am0 = 0.f, ad0 = 0.f, am1 = 0.f, ad1 = 0.f;
        F4(0, am0, ad0) F4(1, am1, ad1)
        F4(2, am0, ad0) F4(3, am1, ad1)
        F4(4, am0, ad0) F4(5, am1, ad1)
        if (u < 4) { F4(6, am0, ad0) }

        float s_ = fmaf(-0.98f, am0 + am1, -0.02f * (ad0 + ad1));
        s_ += __shfl_xor(s_, 1);
        s_ += __shfl_xor(s_, 2);
        s_ += __shfl_xor(s_, 4);
        s_ += __shfl_xor(s_, 8);

        if (u == 0 && cand < NCAND)
            out[(size_t)b * NCAND + cand] = base + s_;
    }
#undef F4
#undef E
}

extern "C" void kernel_launch(void* const* d_in, const int* in_sizes, int n_in,
                              void* d_out, int out_size, void* d_ws, size_t ws_size,
                              hipStream_t stream) {
    const float* ent   = (const float*)d_in[0];
    const float* relc  = (const float*)d_in[1];
    const float* relo  = (const float*)d_in[2];
    const float* onev  = (const float*)d_in[3];
    const int*   pairs = (const int*)d_in[4];
    const int*   cidx  = (const int*)d_in[5];
    float*       out   = (float*)d_out;

    const size_t entB = (size_t)NENT * DIM * 2;      // 11,632,800 (16B-aligned)
    const size_t qB   = (size_t)B * DIM * 2;         // 25,600
    const size_t need = entB + 2 * qB + B * sizeof(float);
    const int grid = 8 * 8 * 32;                     // 2048

    if (ws_size >= need) {
        unsigned char* w = (unsigned char*)d_ws;
        uint4*    ent16 = (uint4*)w;
        _Float16* q16   = (_Float16*)(w + entB);
        _Float16* o16   = (_Float16*)(w + entB + qB);
        float*    baseg = (float*)(w + entB + 2 * qB);

        setup_kernel<<<CVTBLK + B, THREADS, 0, stream>>>(
            ent, relc, relo, onev, pairs, ent16, q16, o16, baseg);
        score_f16<<<grid, THREADS, 0, stream>>>(
            ent16, (const uint4*)q16, (const uint4*)o16, baseg, cidx, out);
    } else {
        score_f32<<<grid, THREADS, 0, stream>>>(ent, relc, relo, onev, pairs, cidx, out);
    }
}